// Round 2
// baseline (20.994 us; speedup 1.0000x reference)
//
#include <hip/hip_runtime.h>
#include <math.h>

#define DGROUPS 64
#define NG      256
#define DIM     512
#define LPAR    8
#define KNEG    32
#define PPAIRS  (DGROUPS - LPAR)      // 56
#define NCHUNKS 16
#define CHUNK   (NG / NCHUNKS)        // 16 rows per A-block
#define CEPS    1e-8f
#define INV_T   10.0f                 // 1 / TEMP

#define NB_A    (DGROUPS * NCHUNKS)   // 1024 A-blocks
#define NB_K1   (NB_A + PPAIRS)       // + 56 neg-blocks

// ws layout (floats):
//   [0, NB_A*DIM)        partial sums: partial[d*NCHUNKS + c][DIM]   (2 MB)
//   [WS_EN,   +56)       en[p]   = sum_dim exp(sim_neg/T)
//   [WS_LOSS, +56)       loss[p]
//   [WS_CNT]             int ticket counter
#define WS_EN   (NB_A * DIM)
#define WS_LOSS (WS_EN + 64)
#define WS_CNT  (WS_LOSS + 64)

__device__ __forceinline__ void f4acc(float4& a, const float4 v) {
    a.x += v.x; a.y += v.y; a.z += v.z; a.w += v.w;
}

// ---------------- K1: fused {embs partial sums} + {neg gather cosine} ----------------
// blocks [0, NB_A): partial sums.  blocks [NB_A, NB_A+56): neg part.  128 threads.
__global__ void k1_fused(const float* __restrict__ embs,
                         const float* __restrict__ g1, const float* __restrict__ g2,
                         const int* __restrict__ neg1, const int* __restrict__ neg2,
                         float* __restrict__ ws) {
    const int b = blockIdx.x;
    const int t = threadIdx.x;                 // 0..127 (float4 column)

    if (b < NB_A) {
        // -------- partial sum over CHUNK rows of group d --------
        const int d = b >> 4;
        const int c = b & 15;
        const float4* src = (const float4*)(embs + (size_t)d * NG * DIM);
        float4 acc = make_float4(0.f, 0.f, 0.f, 0.f);
        int idx = (c * CHUNK) * (DIM / 4) + t;
        #pragma unroll
        for (int n = 0; n < CHUNK; ++n) {
            f4acc(acc, src[idx]);
            idx += DIM / 4;
        }
        ((float4*)(ws + (size_t)b * DIM))[t] = acc;
    } else {
        // -------- neg part: en[p] = sum_dim exp(sim_neg[p,dim]/T) --------
        const int p = b - NB_A;
        if (p == 0 && t == 0) ((int*)(ws + WS_CNT))[0] = 0;   // reset ticket for K2

        __shared__ int i1[KNEG], i2[KNEG];
        if (t < KNEG)          i1[t] = neg1[p * KNEG + t];
        else if (t < 2 * KNEG) i2[t - KNEG] = neg2[p * KNEG + (t - KNEG)];
        __syncthreads();

        float4 sab = make_float4(0.f,0.f,0.f,0.f);
        float4 saa = make_float4(0.f,0.f,0.f,0.f);
        float4 sbb = make_float4(0.f,0.f,0.f,0.f);
        #pragma unroll 8
        for (int k = 0; k < KNEG; ++k) {
            float4 a = ((const float4*)g1)[(size_t)i1[k] * (DIM/4) + t];
            float4 bb = ((const float4*)g2)[(size_t)i2[k] * (DIM/4) + t];
            sab.x += a.x*bb.x; sab.y += a.y*bb.y; sab.z += a.z*bb.z; sab.w += a.w*bb.w;
            saa.x += a.x*a.x;  saa.y += a.y*a.y;  saa.z += a.z*a.z;  saa.w += a.w*a.w;
            sbb.x += bb.x*bb.x; sbb.y += bb.y*bb.y; sbb.z += bb.z*bb.z; sbb.w += bb.w*bb.w;
        }
        float e =
            expf(INV_T * sab.x / (fmaxf(sqrtf(saa.x), CEPS) * fmaxf(sqrtf(sbb.x), CEPS))) +
            expf(INV_T * sab.y / (fmaxf(sqrtf(saa.y), CEPS) * fmaxf(sqrtf(sbb.y), CEPS))) +
            expf(INV_T * sab.z / (fmaxf(sqrtf(saa.z), CEPS) * fmaxf(sqrtf(sbb.z), CEPS))) +
            expf(INV_T * sab.w / (fmaxf(sqrtf(saa.w), CEPS) * fmaxf(sqrtf(sbb.w), CEPS)));

        #pragma unroll
        for (int off = 32; off >= 1; off >>= 1)
            e += __shfl_down(e, off, 64);
        __shared__ float red[2];
        const int wave = t >> 6, lane = t & 63;
        if (lane == 0) red[wave] = e;
        __syncthreads();
        if (t == 0) ws[WS_EN + p] = red[0] + red[1];
    }
}

// ---------------- K2: pos cosine + loss + last-block final reduce ----------------
// 56 blocks × 128 threads
__global__ void k2_pos_final(const float* __restrict__ ws, float* __restrict__ ws_mut,
                             float* __restrict__ out) {
    const int p = blockIdx.x;
    const int t = threadIdx.x;

    float4 si = make_float4(0.f,0.f,0.f,0.f);
    float4 sj = make_float4(0.f,0.f,0.f,0.f);
    #pragma unroll
    for (int c = 0; c < NCHUNKS; ++c) {
        f4acc(si, ((const float4*)ws)[(size_t)(p * NCHUNKS + c) * (DIM/4) + t]);
        f4acc(sj, ((const float4*)ws)[(size_t)((p + LPAR) * NCHUNKS + c) * (DIM/4) + t]);
    }
    float dot = si.x*sj.x + si.y*sj.y + si.z*sj.z + si.w*sj.w;
    float na  = si.x*si.x + si.y*si.y + si.z*si.z + si.w*si.w;
    float nb  = sj.x*sj.x + sj.y*sj.y + sj.z*sj.z + sj.w*sj.w;

    #pragma unroll
    for (int off = 32; off >= 1; off >>= 1) {
        dot += __shfl_down(dot, off, 64);
        na  += __shfl_down(na,  off, 64);
        nb  += __shfl_down(nb,  off, 64);
    }
    __shared__ float red[3][2];
    __shared__ int is_last;
    const int wave = t >> 6, lane = t & 63;
    if (lane == 0) { red[0][wave] = dot; red[1][wave] = na; red[2][wave] = nb; }
    if (t == 0) is_last = 0;
    __syncthreads();

    if (t == 0) {
        float dd = red[0][0] + red[0][1];
        float aa = red[1][0] + red[1][1];
        float bb = red[2][0] + red[2][1];
        float pos = dd / (fmaxf(sqrtf(aa), CEPS) * fmaxf(sqrtf(bb), CEPS));
        float pp  = pos * INV_T;
        float en  = ws[WS_EN + p];
        float loss = logf(expf(pp) + en) - pp;     // -log(num/den)
        __hip_atomic_store(&ws_mut[WS_LOSS + p], loss,
                           __ATOMIC_RELEASE, __HIP_MEMORY_SCOPE_AGENT);
        int ticket = __hip_atomic_fetch_add((int*)(ws_mut + WS_CNT), 1,
                                            __ATOMIC_ACQ_REL, __HIP_MEMORY_SCOPE_AGENT);
        if (ticket == PPAIRS - 1) is_last = 1;
    }
    __syncthreads();

    if (is_last) {
        __threadfence();
        float l = 0.f;
        if (t < PPAIRS)
            l = __hip_atomic_load(&ws_mut[WS_LOSS + t],
                                  __ATOMIC_ACQUIRE, __HIP_MEMORY_SCOPE_AGENT);
        if (t < 64) {
            #pragma unroll
            for (int off = 32; off >= 1; off >>= 1)
                l += __shfl_down(l, off, 64);
            if (t == 0) out[0] = 2.0f * l;
        }
    }
}

extern "C" void kernel_launch(void* const* d_in, const int* in_sizes, int n_in,
                              void* d_out, int out_size, void* d_ws, size_t ws_size,
                              hipStream_t stream) {
    const float* embs = (const float*)d_in[0];
    // d_in[1] = g0 (dead on this output path)
    const float* g1   = (const float*)d_in[2];
    const float* g2   = (const float*)d_in[3];
    const int*   neg1 = (const int*)d_in[4];
    const int*   neg2 = (const int*)d_in[5];
    float* ws  = (float*)d_ws;
    float* out = (float*)d_out;

    k1_fused<<<NB_K1, 128, 0, stream>>>(embs, g1, g2, neg1, neg2, ws);
    k2_pos_final<<<PPAIRS, 128, 0, stream>>>(ws, ws, out);
}